// Round 1
// 1129.411 us; speedup vs baseline: 1.0710x; 1.0710x over previous
//
#include <hip/hip_runtime.h>
#include <cstdint>
#include <cstddef>

typedef __bf16 bf16;
typedef __attribute__((ext_vector_type(8))) __bf16 bf16x8;
typedef __attribute__((ext_vector_type(4))) float f32x4;

#define NB 256
#define NS 128
#define NH 8
#define NDK 128
#define NP 128
#define NDM 1024

static constexpr float kScale = 0.05103103630798287f;  // 1/sqrt(3*128)
static constexpr float kNeg = -1.0e9f;

static __device__ __forceinline__ f32x4 mfma16(bf16x8 a, bf16x8 b, f32x4 c) {
  return __builtin_amdgcn_mfma_f32_16x16x32_bf16(a, b, c, 0, 0, 0);
}

// async global->LDS, 16B per lane; LDS dest is wave-uniform base + lane*16
static __device__ __forceinline__ void gld_lds16(const bf16* g, bf16* l) {
  __builtin_amdgcn_global_load_lds(
      (const __attribute__((address_space(1))) void*)g,
      (__attribute__((address_space(3))) void*)l, 16, 0, 0);
}

// raw barrier (no vmcnt drain), fenced against scheduler motion
static __device__ __forceinline__ void barx() {
  __builtin_amdgcn_sched_barrier(0);
  __builtin_amdgcn_s_barrier();
  __builtin_amdgcn_sched_barrier(0);
}

// reduce across the 16 lanes sharing (lane>>4)
static __device__ __forceinline__ float red16_max(float v) {
  v = fmaxf(v, __shfl_xor(v, 1, 64));
  v = fmaxf(v, __shfl_xor(v, 2, 64));
  v = fmaxf(v, __shfl_xor(v, 4, 64));
  v = fmaxf(v, __shfl_xor(v, 8, 64));
  return v;
}
static __device__ __forceinline__ float red16_sum(float v) {
  v += __shfl_xor(v, 1, 64);
  v += __shfl_xor(v, 2, 64);
  v += __shfl_xor(v, 4, 64);
  v += __shfl_xor(v, 8, 64);
  return v;
}

// ---------------- prep: transpose+cast weights, cast/transpose rel tables ---
static __device__ void transpose64(const float* __restrict__ src, bf16* __restrict__ dst,
                                   int rows, int cols, int r0, int c0,
                                   float (*t)[65], int tid) {
  const int tr = tid >> 4, tc = tid & 15;
#pragma unroll
  for (int i = 0; i < 4; i++) {
    int r = tr + i * 16;
    float4 v = *(const float4*)&src[(size_t)(r0 + r) * cols + c0 + tc * 4];
    t[r][tc * 4 + 0] = v.x;
    t[r][tc * 4 + 1] = v.y;
    t[r][tc * 4 + 2] = v.z;
    t[r][tc * 4 + 3] = v.w;
  }
  __syncthreads();
#pragma unroll
  for (int i = 0; i < 4; i++) {
    int c = tr + i * 16;
    union { bf16 o[4]; uint64_t u; } pk;
#pragma unroll
    for (int k2 = 0; k2 < 4; k2++) pk.o[k2] = (bf16)t[tc * 4 + k2][c];
    *(uint64_t*)&dst[(size_t)(c0 + c) * rows + r0 + tc * 4] = pk.u;
  }
}

__global__ __launch_bounds__(256) void prep_kernel(
    const float* __restrict__ Wq, const float* __restrict__ Wk,
    const float* __restrict__ Wv, const float* __restrict__ Wo,
    const float* __restrict__ rel_q, const float* __restrict__ rel_k,
    const float* __restrict__ rel_v,
    bf16* __restrict__ Wtq, bf16* __restrict__ Wtk,
    bf16* __restrict__ Wtv, bf16* __restrict__ Wto,
    bf16* __restrict__ rqb, bf16* __restrict__ rkb, bf16* __restrict__ rvt) {
  __shared__ float t[64][65];
  const int tid = threadIdx.x;
  const int z = blockIdx.z;
  if (z < 4) {
    const float* src = (z == 0) ? Wq : (z == 1) ? Wk : (z == 2) ? Wv : Wo;
    bf16* dst = (z == 0) ? Wtq : (z == 1) ? Wtk : (z == 2) ? Wtv : Wto;
    transpose64(src, dst, NDM, NDM, blockIdx.y * 64, blockIdx.x * 64, t, tid);
  } else if (z == 4) {
    int lb = blockIdx.y * 16 + blockIdx.x;
    if (lb < 32) {
      int hh = lb >> 2, tt = lb & 3;
      transpose64(rel_v + (size_t)hh * NP * NDK, rvt + (size_t)hh * NDK * NP,
                  NP, NDK, (tt >> 1) * 64, (tt & 1) * 64, t, tid);
    }
  } else {
    int lb = blockIdx.y * 16 + blockIdx.x;
    if (lb < 128) {
      size_t base = (size_t)lb * 1024 + (size_t)tid * 4;
      float4 a = *(const float4*)&rel_q[base];
      float4 c = *(const float4*)&rel_k[base];
      union { bf16 o[4]; uint64_t u; } pa, pc;
      pa.o[0] = (bf16)a.x; pa.o[1] = (bf16)a.y; pa.o[2] = (bf16)a.z; pa.o[3] = (bf16)a.w;
      pc.o[0] = (bf16)c.x; pc.o[1] = (bf16)c.y; pc.o[2] = (bf16)c.z; pc.o[3] = (bf16)c.w;
      *(uint64_t*)&rqb[base] = pa.u;
      *(uint64_t*)&rkb[base] = pc.u;
    }
  }
}

// ---------------- cast: f32 [32768,1024] -> bf16 ----------------------------
__global__ __launch_bounds__(256) void cast_kernel(
    const float* __restrict__ x0, const float* __restrict__ x1,
    const float* __restrict__ x2,
    bf16* __restrict__ y0, bf16* __restrict__ y1, bf16* __restrict__ y2) {
  const int z = blockIdx.z;
  const float* x = (z == 0) ? x0 : (z == 1) ? x1 : x2;
  bf16* y = (z == 0) ? y0 : (z == 1) ? y1 : y2;
  size_t i = ((size_t)blockIdx.x * 256 + threadIdx.x) * 8;
  float4 a = *(const float4*)&x[i];
  float4 b = *(const float4*)&x[i + 4];
  union { bf16 o[8]; bf16x8 v; } u;
  u.o[0] = (bf16)a.x; u.o[1] = (bf16)a.y; u.o[2] = (bf16)a.z; u.o[3] = (bf16)a.w;
  u.o[4] = (bf16)b.x; u.o[5] = (bf16)b.y; u.o[6] = (bf16)b.z; u.o[7] = (bf16)b.w;
  *(bf16x8*)&y[i] = u.v;
}

// ---------------- 256x256 8-phase pipelined GEMM (T1+T2+T3+T4+T5) -----------
// C[M,N] = A[M,1024] @ W[N,1024]^T ; BK=64; 512 thr = 8 waves (2M x 4N);
// LDS: 2 dbuf x 256x64 bf16 per matrix = 128 KiB. Per wave: 128x64 C tile,
// acc[8][4] f32x4. Per phase: 16 MFMA; ds_reads 12/4/8/0; 1 half-tile stage.
// vmcnt(2) once per K-tile (never 0 in main loop). LDS swizzle:
// byte ^= (row&7)<<4 — linear gld_lds dest + inverse-swizzled global source +
// swizzled ds_read (rule 21: both-sides-or-neither).
#define TSZ (256 * 64)

template <int MODE>  // 0: proj (3x, bf16 scatter [B,H,S,DK]); 1: out (f32 row-major)
__global__ __launch_bounds__(512, 2) void gemm256(
    const bf16* __restrict__ X0, const bf16* __restrict__ X1, const bf16* __restrict__ X2,
    const bf16* __restrict__ W0, const bf16* __restrict__ W1, const bf16* __restrict__ W2,
    const float* __restrict__ b0p, const float* __restrict__ b1p, const float* __restrict__ b2p,
    bf16* __restrict__ Obf0, bf16* __restrict__ Obf1, bf16* __restrict__ Obf2,
    float* __restrict__ Of32) {
  __shared__ __attribute__((aligned(16))) bf16 sA[2 * TSZ];
  __shared__ __attribute__((aligned(16))) bf16 sB[2 * TSZ];

  const int z = blockIdx.z;
  const bf16* X  = (MODE == 1) ? X0 : ((z == 0) ? X0 : (z == 1) ? X1 : X2);
  const bf16* Wt = (MODE == 1) ? W0 : ((z == 0) ? W0 : (z == 1) ? W1 : W2);
  const float* bias = (MODE == 1) ? b0p : ((z == 0) ? b0p : (z == 1) ? b1p : b2p);

  // XCD-aware bijective swizzle: nwg = 4*128 = 512, 512 % 8 == 0.
  // Blocks sharing an A panel (same M0, all 4 N0) land on one XCD.
  const int nx = gridDim.x;
  const int flat = blockIdx.y * nx + blockIdx.x;
  const int cpx = (nx * gridDim.y) >> 3;
  const int swz = (flat & 7) * cpx + (flat >> 3);
  const int M0 = (swz / nx) * 256;
  const int N0 = (swz % nx) * 256;

  const int tid = threadIdx.x, lane = tid & 63, w = tid >> 6;
  const int l15 = lane & 15, l4 = lane >> 4;
  const int wm = w >> 2, wn = w & 3;

  // --- staging geometry: half-tile = 128 rows x 64 cols; wave w covers rows
  // [w*16, w*16+16) via 2 gld_lds16 (8 rows / 1 KiB each). LDS dest linear;
  // the swizzle is applied by permuting the per-lane GLOBAL source column.
  const int lr = lane >> 3;                       // row within 8-row group
  const int scol = ((lane & 7) ^ lr) * 8;         // inverse-swizzled src col (elems)
  const size_t aRow = (size_t)(M0 + w * 16 + lr) * NDM + scol;
  const size_t bRow = (size_t)(N0 + w * 16 + lr) * NDM + scol;
  bf16* const dA = sA + (w * 16) * 64;
  bf16* const dB = sB + (w * 16) * 64;

  auto stA = [&](int bufi, int half, int t) {
    const bf16* s = X + aRow + (size_t)half * 128 * NDM + t * 64;
    bf16* d = dA + bufi * TSZ + half * (128 * 64);
    gld_lds16(s, d);
    gld_lds16(s + 8 * NDM, d + 8 * 64);
  };
  auto stB = [&](int bufi, int half, int t) {
    const bf16* s = Wt + bRow + (size_t)half * 128 * NDM + t * 64;
    bf16* d = dB + bufi * TSZ + half * (128 * 64);
    gld_lds16(s, d);
    gld_lds16(s + 8 * NDM, d + 8 * 64);
  };

  f32x4 acc[8][4];
#pragma unroll
  for (int mt = 0; mt < 8; mt++)
#pragma unroll
    for (int nt = 0; nt < 4; nt++) acc[mt][nt] = (f32x4){0.f, 0.f, 0.f, 0.f};

  // swizzled ds_read column offsets (elements); row&7 == l15&7 for all frags
  const int kc0 = (l4 * 8) ^ ((l15 & 7) * 8);
  const int kc1 = (32 + l4 * 8) ^ ((l15 & 7) * 8);
  int arow[8], brow[4];
#pragma unroll
  for (int mt = 0; mt < 8; mt++) arow[mt] = (wm * 128 + mt * 16 + l15) * 64;
#pragma unroll
  for (int nt = 0; nt < 4; nt++) brow[nt] = (wn * 64 + nt * 16 + l15) * 64;

  // prologue: stage tile 0 fully (8 loads/wave outstanding)
  stA(0, 0, 0); stA(0, 1, 0); stB(0, 0, 0); stB(0, 1, 0);

  const int NT = NDM / 64;  // 16
  for (int t = 0; t < NT; ++t) {
    const int cur = t & 1, nxt = cur ^ 1;
    const bf16* cA = sA + cur * TSZ;
    const bf16* cB = sB + cur * TSZ;
    const bool pf = (t + 1 < NT);

    // ---- P0: prefetch A-half0(t+1); counted wait; read a0,b0; MFMA kk0 mt0-3
    if (pf) {
      stA(nxt, 0, t + 1);
      asm volatile("s_waitcnt vmcnt(2)" ::: "memory");  // tile-t loads done; 2 in flight
    } else {
      asm volatile("s_waitcnt vmcnt(0)" ::: "memory");
    }
    barx();  // all waves' tile-t stages visible
    bf16x8 a0[8], b0[4], a1[8], b1[4];
#pragma unroll
    for (int mt = 0; mt < 4; mt++) a0[mt] = *(const bf16x8*)&cA[arow[mt] + kc0];
#pragma unroll
    for (int nt = 0; nt < 4; nt++) b0[nt] = *(const bf16x8*)&cB[brow[nt] + kc0];
#pragma unroll
    for (int mt = 4; mt < 8; mt++) a0[mt] = *(const bf16x8*)&cA[arow[mt] + kc0];
    __builtin_amdgcn_s_setprio(1);
#pragma unroll
    for (int mt = 0; mt < 4; mt++)
#pragma unroll
      for (int nt = 0; nt < 4; nt++) acc[mt][nt] = mfma16(a0[mt], b0[nt], acc[mt][nt]);
    __builtin_amdgcn_s_setprio(0);
    barx();

    // ---- P1: read a1[0..3]; prefetch A-half1(t+1); MFMA kk0 mt4-7
#pragma unroll
    for (int mt = 0; mt < 4; mt++) a1[mt] = *(const bf16x8*)&cA[arow[mt] + kc1];
    if (pf) stA(nxt, 1, t + 1);
    barx();
    __builtin_amdgcn_s_setprio(1);
#pragma unroll
    for (int mt = 4; mt < 8; mt++)
#pragma unroll
      for (int nt = 0; nt < 4; nt++) acc[mt][nt] = mfma16(a0[mt], b0[nt], acc[mt][nt]);
    __builtin_amdgcn_s_setprio(0);
    barx();

    // ---- P2: read a1[4..7], b1; prefetch B-half0(t+1); MFMA kk1 mt0-3
#pragma unroll
    for (int nt = 0; nt < 4; nt++) b1[nt] = *(const bf16x8*)&cB[brow[nt] + kc1];
#pragma unroll
    for (int mt = 4; mt < 8; mt++) a1[mt] = *(const bf16x8*)&cA[arow[mt] + kc1];
    if (pf) stB(nxt, 0, t + 1);
    barx();
    __builtin_amdgcn_s_setprio(1);
#pragma unroll
    for (int mt = 0; mt < 4; mt++)
#pragma unroll
      for (int nt = 0; nt < 4; nt++) acc[mt][nt] = mfma16(a1[mt], b1[nt], acc[mt][nt]);
    __builtin_amdgcn_s_setprio(0);
    barx();

    // ---- P3: prefetch B-half1(t+1); MFMA kk1 mt4-7
    if (pf) stB(nxt, 1, t + 1);
    barx();
    __builtin_amdgcn_s_setprio(1);
#pragma unroll
    for (int mt = 4; mt < 8; mt++)
#pragma unroll
      for (int nt = 0; nt < 4; nt++) acc[mt][nt] = mfma16(a1[mt], b1[nt], acc[mt][nt]);
    __builtin_amdgcn_s_setprio(0);
    barx();
  }

  // ---- epilogue
  if (MODE == 0) {
    bf16* O = (z == 0) ? Obf0 : (z == 1) ? Obf1 : Obf2;
#pragma unroll
    for (int mt = 0; mt < 8; mt++) {
#pragma unroll
      for (int nt = 0; nt < 4; nt++) {
        const int n = N0 + wn * 64 + nt * 16 + l15;
        const float bv_ = bias[n];
        const int h = n >> 7, dk = n & 127;
#pragma unroll
        for (int r = 0; r < 4; r++) {
          const int m = M0 + wm * 128 + mt * 16 + l4 * 4 + r;
          const int b = m >> 7, s = m & 127;
          O[(((size_t)b * NH + h) * NS + s) * NDK + dk] = (bf16)(acc[mt][nt][r] + bv_);
        }
      }
    }
  } else {
#pragma unroll
    for (int mt = 0; mt < 8; mt++) {
#pragma unroll
      for (int nt = 0; nt < 4; nt++) {
        const int n = N0 + wn * 64 + nt * 16 + l15;
        const float bv_ = bias[n];
#pragma unroll
        for (int r = 0; r < 4; r++) {
          const int m = M0 + wm * 128 + mt * 16 + l4 * 4 + r;
          Of32[(size_t)m * NDM + n] = acc[mt][nt][r] + bv_;
        }
      }
    }
  }
}

// ---------------- V tile transpose: [BH][S][DK] -> [BH][DK][S] (bf16) -------
__global__ __launch_bounds__(256) void vt_kernel(const bf16* __restrict__ Vin,
                                                 bf16* __restrict__ Vt) {
  __shared__ __attribute__((aligned(16))) bf16 t[64][72];
  const size_t base = (size_t)blockIdx.z * (NS * NDK);
  const int r0 = blockIdx.y * 64, c0 = blockIdx.x * 64;
  const int tid = threadIdx.x;
  const int tr = tid >> 3, tc8 = tid & 7;
#pragma unroll
  for (int i = 0; i < 2; i++) {
    int r = tr + i * 32;
    *(bf16x8*)&t[r][tc8 * 8] = *(const bf16x8*)&Vin[base + (size_t)(r0 + r) * NDK + c0 + tc8 * 8];
  }
  __syncthreads();
#pragma unroll
  for (int i = 0; i < 2; i++) {
    int c = tr + i * 32;
    bf16x8 o;
#pragma unroll
    for (int k2 = 0; k2 < 8; k2++) o[k2] = t[tc8 * 8 + k2][c];
    *(bf16x8*)&Vt[base + (size_t)(c0 + c) * NS + r0 + tc8 * 8] = o;
  }
}

// ---------------- attention: one block per (b,h) ----------------------------
__global__ __launch_bounds__(256, 1) void attn_kernel(
    const bf16* __restrict__ Qg, const bf16* __restrict__ Kg, const bf16* __restrict__ Vtg,
    const bf16* __restrict__ relq, const bf16* __restrict__ relk, const bf16* __restrict__ relvT,
    const int* __restrict__ qpos, const int* __restrict__ kvpos,
    bf16* __restrict__ ctx) {
  constexpr int LD = 136;
  __shared__ __attribute__((aligned(16))) bf16 R0[128 * LD];
  __shared__ __attribute__((aligned(16))) bf16 R1[128 * LD];
  __shared__ __attribute__((aligned(16))) bf16 R2[128 * LD];
  __shared__ __attribute__((aligned(16))) bf16 R3[128 * LD];

  const int bh = blockIdx.x;
  const int b = bh >> 3, h = bh & 7;
  const int tid = threadIdx.x, lane = tid & 63, w = tid >> 6;
  const int l15 = lane & 15, l4 = lane >> 4;
  const int m0 = w * 32;

  const size_t tb = (size_t)bh * (NS * NDK);
  const bf16* Qp = Qg + tb;
  const bf16* Kp = Kg + tb;
  const bf16* Vp = Vtg + tb;
  const bf16* rq = relq + (size_t)h * NP * NDK;
  const bf16* rk = relk + (size_t)h * NP * NDK;
  const bf16* rv = relvT + (size_t)h * NDK * NP;
  const int* qpp = qpos + (size_t)bh * NS * NS;
  const int* kpp = kvpos + (size_t)bh * NS * NS;

  auto load_tile = [&](bf16* dst, const bf16* src) {
    const int r = tid >> 4, c8 = tid & 15;
#pragma unroll
    for (int i = 0; i < 8; i++) {
      int rr = r + i * 16;
      *(bf16x8*)&dst[rr * LD + c8 * 8] = *(const bf16x8*)&src[rr * 128 + c8 * 8];
    }
  };
  auto gemmNT = [&](const bf16* A, const bf16* Bm, f32x4 (&acc)[2][8]) {
#pragma unroll
    for (int kk = 0; kk < 128; kk += 32) {
      bf16x8 a0 = *(const bf16x8*)&A[(m0 + l15) * LD + kk + l4 * 8];
      bf16x8 a1 = *(const bf16x8*)&A[(m0 + 16 + l15) * LD + kk + l4 * 8];
#pragma unroll
      for (int nt = 0; nt < 8; nt++) {
        bf16x8 bb = *(const bf16x8*)&Bm[(nt * 16 + l15) * LD + kk + l4 * 8];
        acc[0][nt] = mfma16(a0, bb, acc[0][nt]);
        acc[1][nt] = mfma16(a1, bb, acc[1][nt]);
      }
    }
  };

  load_tile(R0, Qp);
  load_tile(R1, Kp);
  load_tile(R2, rq);
  __syncthreads();

  {
    f32x4 acc[2][8];
#pragma unroll
    for (int mt = 0; mt < 2; mt++)
#pragma unroll
      for (int nt = 0; nt < 8; nt++) acc[mt][nt] = (f32x4){0.f, 0.f, 0.f, 0.f};
    gemmNT(R2, R1, acc);
#pragma unroll
    for (int mt = 0; mt < 2; mt++)
#pragma unroll
      for (int nt = 0; nt < 8; nt++)
#pragma unroll
        for (int r = 0; r < 4; r++) {
          int pp = m0 + mt * 16 + l4 * 4 + r;
          int j = nt * 16 + l15;
          R3[pp * LD + j] = (bf16)(acc[mt][nt][r] * kScale);
        }
  }
  f32x4 sc[2][8];
#pragma unroll
  for (int mt = 0; mt < 2; mt++)
#pragma unroll
    for (int nt = 0; nt < 8; nt++) sc[mt][nt] = (f32x4){0.f, 0.f, 0.f, 0.f};
  gemmNT(R0, R1, sc);
  __syncthreads();

  load_tile(R2, rk);
  __syncthreads();

  {
    f32x4 acc[2][8];
#pragma unroll
    for (int mt = 0; mt < 2; mt++)
#pragma unroll
      for (int nt = 0; nt < 8; nt++) acc[mt][nt] = (f32x4){0.f, 0.f, 0.f, 0.f};
    gemmNT(R0, R2, acc);
#pragma unroll
    for (int mt = 0; mt < 2; mt++)
#pragma unroll
      for (int nt = 0; nt < 8; nt++)
#pragma unroll
        for (int r = 0; r < 4; r++) {
          int i = m0 + mt * 16 + l4 * 4 + r;
          int pp = nt * 16 + l15;
          R1[i * LD + pp] = (bf16)(acc[mt][nt][r] * kScale);
        }
  }

  unsigned long long keep = 0ull;
#pragma unroll
  for (int mt = 0; mt < 2; mt++)
#pragma unroll
    for (int nt = 0; nt < 8; nt++)
#pragma unroll
      for (int r = 0; r < 4; r++) {
        int i = m0 + mt * 16 + l4 * 4 + r;
        int j = nt * 16 + l15;
        int qv = qpp[i * NS + j];
        int kv = kpp[i * NS + j];
        float v = sc[mt][nt][r] * kScale + (float)R3[qv * LD + j] + (float)R1[i * LD + kv];
        sc[mt][nt][r] = v;
        if (qv == 0 || i == 0) keep |= 1ull << (mt * 32 + nt * 4 + r);
      }
  float rmx[2][4];
#pragma unroll
  for (int mt = 0; mt < 2; mt++)
#pragma unroll
    for (int r = 0; r < 4; r++) {
      float m = -3.0e38f;
#pragma unroll
      for (int nt = 0; nt < 8; nt++) m = fmaxf(m, sc[mt][nt][r]);
      rmx[mt][r] = red16_max(m);
    }
#pragma unroll
  for (int mt = 0; mt < 2; mt++)
#pragma unroll
    for (int nt = 0; nt < 8; nt++)
#pragma unroll
      for (int r = 0; r < 4; r++) {
        float v = sc[mt][nt][r] - rmx[mt][r];
        if (!((keep >> (mt * 32 + nt * 4 + r)) & 1ull)) v = kNeg;
        sc[mt][nt][r] = v;
      }
  float m2[2][4], inv[2][4];
#pragma unroll
  for (int mt = 0; mt < 2; mt++)
#pragma unroll
    for (int r = 0; r < 4; r++) {
      float m = -3.0e38f;
#pragma unroll
      for (int nt = 0; nt < 8; nt++) m = fmaxf(m, sc[mt][nt][r]);
      m2[mt][r] = red16_max(m);
    }
#pragma unroll
  for (int mt = 0; mt < 2; mt++)
#pragma unroll
    for (int nt = 0; nt < 8; nt++)
#pragma unroll
      for (int r = 0; r < 4; r++) sc[mt][nt][r] = __expf(sc[mt][nt][r] - m2[mt][r]);
#pragma unroll
  for (int mt = 0; mt < 2; mt++)
#pragma unroll
    for (int r = 0; r < 4; r++) {
      float s = 0.f;
#pragma unroll
      for (int nt = 0; nt < 8; nt++) s += sc[mt][nt][r];
      inv[mt][r] = 1.0f / red16_sum(s);
    }
#pragma unroll
  for (int mt = 0; mt < 2; mt++)
#pragma unroll
    for (int nt = 0; nt < 8; nt++)
#pragma unroll
      for (int r = 0; r < 4; r++) sc[mt][nt][r] *= inv[mt][r];
  __syncthreads();

#pragma unroll
  for (int mt = 0; mt < 2; mt++)
#pragma unroll
    for (int nt = 0; nt < 8; nt++)
#pragma unroll
      for (int r = 0; r < 4; r++) {
        int i = m0 + mt * 16 + l4 * 4 + r;
        int j = nt * 16 + l15;
        R3[i * LD + j] = (bf16)sc[mt][nt][r];
      }
  load_tile(R0, Vp);
  load_tile(R1, rv);
  __syncthreads();

  {
    f32x4 acc2[2][8];
#pragma unroll
    for (int mt = 0; mt < 2; mt++)
#pragma unroll
      for (int nt = 0; nt < 8; nt++) acc2[mt][nt] = (f32x4){0.f, 0.f, 0.f, 0.f};
    gemmNT(R3, R1, acc2);
#pragma unroll
    for (int mt = 0; mt < 2; mt++)
#pragma unroll
      for (int nt = 0; nt < 8; nt++)
#pragma unroll
        for (int r = 0; r < 4; r++) {
          int i = m0 + mt * 16 + l4 * 4 + r;
          int d = nt * 16 + l15;
          R2[i * LD + d] = (bf16)acc2[mt][nt][r];
        }
  }
  {
    f32x4 acc1[2][8];
#pragma unroll
    for (int mt = 0; mt < 2; mt++)
#pragma unroll
      for (int nt = 0; nt < 8; nt++) acc1[mt][nt] = (f32x4){0.f, 0.f, 0.f, 0.f};
    gemmNT(R3, R0, acc1);
#pragma unroll
    for (int mt = 0; mt < 2; mt++)
#pragma unroll
      for (int nt = 0; nt < 8; nt++)
#pragma unroll
        for (int r = 0; r < 4; r++) {
          int i = m0 + mt * 16 + l4 * 4 + r;
          int d = nt * 16 + l15;
          int kv = kpp[i * NS + d];
          float v = acc1[mt][nt][r] + (float)R2[i * LD + kv];
          ctx[(((size_t)b * NS + i) * NH + h) * NDK + d] = (bf16)v;
        }
  }
}

extern "C" void kernel_launch(void* const* d_in, const int* in_sizes, int n_in,
                              void* d_out, int out_size, void* d_ws, size_t ws_size,
                              hipStream_t stream) {
  const float* query = (const float*)d_in[0];
  const float* key   = (const float*)d_in[1];
  const float* value = (const float*)d_in[2];
  const int* qpos    = (const int*)d_in[3];
  const int* kvpos   = (const int*)d_in[4];
  const float* rel_q = (const float*)d_in[5];
  const float* rel_k = (const float*)d_in[6];
  const float* rel_v = (const float*)d_in[7];
  const float* Wq = (const float*)d_in[8];
  const float* bq = (const float*)d_in[9];
  const float* Wk = (const float*)d_in[10];
  const float* bk = (const float*)d_in[11];
  const float* Wv = (const float*)d_in[12];
  const float* bv = (const float*)d_in[13];
  const float* Wo = (const float*)d_in[14];
  const float* bo = (const float*)d_in[15];
  float* out = (float*)d_out;

  char* p = (char*)d_ws;
  size_t off = 0;
  auto take = [&](size_t n) {
    char* r = p + off;
    off += (n + 255) & ~(size_t)255;
    return r;
  };
  bf16* Wtq = (bf16*)take((size_t)NDM * NDM * 2);
  bf16* Wtk = (bf16*)take((size_t)NDM * NDM * 2);
  bf16* Wtv = (bf16*)take((size_t)NDM * NDM * 2);
  bf16* Wto = (bf16*)take((size_t)NDM * NDM * 2);
  bf16* rqb = (bf16*)take((size_t)NH * NP * NDK * 2);
  bf16* rkb = (bf16*)take((size_t)NH * NP * NDK * 2);
  bf16* rvt = (bf16*)take((size_t)NH * NDK * NP * 2);
  const size_t big = (size_t)NB * NH * NS * NDK * 2;  // 64 MiB
  bf16* qws  = (bf16*)take(big);
  bf16* kws  = (bf16*)take(big);
  bf16* vws  = (bf16*)take(big);
  bf16* vtws = (bf16*)take(big);
  bf16* ctxw = (bf16*)take(big);
  bf16* xtra = (bf16*)take(big);
  // cast buffers alias later-life buffers (dead before vt/attn write them):
  bf16* xq = vtws;  // vtws written only in vt_kernel (after proj)
  bf16* xk = ctxw;  // ctxw written only in attn (after proj)
  bf16* xv = xtra;

  hipLaunchKernelGGL(prep_kernel, dim3(16, 16, 6), dim3(256), 0, stream,
                     Wq, Wk, Wv, Wo, rel_q, rel_k, rel_v,
                     Wtq, Wtk, Wtv, Wto, rqb, rkb, rvt);
  hipLaunchKernelGGL(cast_kernel, dim3((NB * NS * NDM) / (256 * 8), 1, 3), dim3(256), 0, stream,
                     query, key, value, xq, xk, xv);
  hipLaunchKernelGGL((gemm256<0>), dim3(4, 128, 3), dim3(512), 0, stream,
                     xq, xk, xv, Wtq, Wtk, Wtv, bq, bk, bv, qws, kws, vws, (float*)nullptr);
  hipLaunchKernelGGL(vt_kernel, dim3(2, 2, NB * NH), dim3(256), 0, stream, vws, vtws);
  hipLaunchKernelGGL(attn_kernel, dim3(NB * NH), dim3(256), 0, stream,
                     qws, kws, vtws, rqb, rkb, rvt, qpos, kvpos, ctxw);
  hipLaunchKernelGGL((gemm256<1>), dim3(4, 128, 1), dim3(512), 0, stream,
                     ctxw, (const bf16*)nullptr, (const bf16*)nullptr,
                     Wto, (const bf16*)nullptr, (const bf16*)nullptr,
                     bo, (const float*)nullptr, (const float*)nullptr,
                     (bf16*)nullptr, (bf16*)nullptr, (bf16*)nullptr, out);
}

// Round 2
// 1124.669 us; speedup vs baseline: 1.0755x; 1.0042x over previous
//
#include <hip/hip_runtime.h>
#include <cstdint>
#include <cstddef>

typedef __bf16 bf16;
typedef __attribute__((ext_vector_type(8))) __bf16 bf16x8;
typedef __attribute__((ext_vector_type(4))) float f32x4;

#define NB 256
#define NS 128
#define NH 8
#define NDK 128
#define NP 128
#define NDM 1024

static constexpr float kScale = 0.05103103630798287f;  // 1/sqrt(3*128)
static constexpr float kNeg = -1.0e9f;

static __device__ __forceinline__ f32x4 mfma16(bf16x8 a, bf16x8 b, f32x4 c) {
  return __builtin_amdgcn_mfma_f32_16x16x32_bf16(a, b, c, 0, 0, 0);
}

// async global->LDS, 16B per lane; LDS dest is wave-uniform base + lane*16
static __device__ __forceinline__ void gld_lds16(const bf16* g, bf16* l) {
  __builtin_amdgcn_global_load_lds(
      (const __attribute__((address_space(1))) void*)g,
      (__attribute__((address_space(3))) void*)l, 16, 0, 0);
}

// raw barrier (no vmcnt drain), fenced against scheduler motion
static __device__ __forceinline__ void barx() {
  __builtin_amdgcn_sched_barrier(0);
  __builtin_amdgcn_s_barrier();
  __builtin_amdgcn_sched_barrier(0);
}

// reduce across the 16 lanes sharing (lane>>4)
static __device__ __forceinline__ float red16_max(float v) {
  v = fmaxf(v, __shfl_xor(v, 1, 64));
  v = fmaxf(v, __shfl_xor(v, 2, 64));
  v = fmaxf(v, __shfl_xor(v, 4, 64));
  v = fmaxf(v, __shfl_xor(v, 8, 64));
  return v;
}
static __device__ __forceinline__ float red16_sum(float v) {
  v += __shfl_xor(v, 1, 64);
  v += __shfl_xor(v, 2, 64);
  v += __shfl_xor(v, 4, 64);
  v += __shfl_xor(v, 8, 64);
  return v;
}

// ---------------- prep: transpose+cast weights, cast/transpose rel tables ---
static __device__ void transpose64(const float* __restrict__ src, bf16* __restrict__ dst,
                                   int rows, int cols, int r0, int c0,
                                   float (*t)[65], int tid) {
  const int tr = tid >> 4, tc = tid & 15;
#pragma unroll
  for (int i = 0; i < 4; i++) {
    int r = tr + i * 16;
    float4 v = *(const float4*)&src[(size_t)(r0 + r) * cols + c0 + tc * 4];
    t[r][tc * 4 + 0] = v.x;
    t[r][tc * 4 + 1] = v.y;
    t[r][tc * 4 + 2] = v.z;
    t[r][tc * 4 + 3] = v.w;
  }
  __syncthreads();
#pragma unroll
  for (int i = 0; i < 4; i++) {
    int c = tr + i * 16;
    union { bf16 o[4]; uint64_t u; } pk;
#pragma unroll
    for (int k2 = 0; k2 < 4; k2++) pk.o[k2] = (bf16)t[tc * 4 + k2][c];
    *(uint64_t*)&dst[(size_t)(c0 + c) * rows + r0 + tc * 4] = pk.u;
  }
}

__global__ __launch_bounds__(256) void prep_kernel(
    const float* __restrict__ Wq, const float* __restrict__ Wk,
    const float* __restrict__ Wv, const float* __restrict__ Wo,
    const float* __restrict__ rel_q, const float* __restrict__ rel_k,
    const float* __restrict__ rel_v,
    bf16* __restrict__ Wtq, bf16* __restrict__ Wtk,
    bf16* __restrict__ Wtv, bf16* __restrict__ Wto,
    bf16* __restrict__ rqb, bf16* __restrict__ rkb, bf16* __restrict__ rvt) {
  __shared__ float t[64][65];
  const int tid = threadIdx.x;
  const int z = blockIdx.z;
  if (z < 4) {
    const float* src = (z == 0) ? Wq : (z == 1) ? Wk : (z == 2) ? Wv : Wo;
    bf16* dst = (z == 0) ? Wtq : (z == 1) ? Wtk : (z == 2) ? Wtv : Wto;
    transpose64(src, dst, NDM, NDM, blockIdx.y * 64, blockIdx.x * 64, t, tid);
  } else if (z == 4) {
    int lb = blockIdx.y * 16 + blockIdx.x;
    if (lb < 32) {
      int hh = lb >> 2, tt = lb & 3;
      transpose64(rel_v + (size_t)hh * NP * NDK, rvt + (size_t)hh * NDK * NP,
                  NP, NDK, (tt >> 1) * 64, (tt & 1) * 64, t, tid);
    }
  } else {
    int lb = blockIdx.y * 16 + blockIdx.x;
    if (lb < 128) {
      size_t base = (size_t)lb * 1024 + (size_t)tid * 4;
      float4 a = *(const float4*)&rel_q[base];
      float4 c = *(const float4*)&rel_k[base];
      union { bf16 o[4]; uint64_t u; } pa, pc;
      pa.o[0] = (bf16)a.x; pa.o[1] = (bf16)a.y; pa.o[2] = (bf16)a.z; pa.o[3] = (bf16)a.w;
      pc.o[0] = (bf16)c.x; pc.o[1] = (bf16)c.y; pc.o[2] = (bf16)c.z; pc.o[3] = (bf16)c.w;
      *(uint64_t*)&rqb[base] = pa.u;
      *(uint64_t*)&rkb[base] = pc.u;
    }
  }
}

// ---------------- cast: f32 [32768,1024] -> bf16 ----------------------------
__global__ __launch_bounds__(256) void cast_kernel(
    const float* __restrict__ x0, const float* __restrict__ x1,
    const float* __restrict__ x2,
    bf16* __restrict__ y0, bf16* __restrict__ y1, bf16* __restrict__ y2) {
  const int z = blockIdx.z;
  const float* x = (z == 0) ? x0 : (z == 1) ? x1 : x2;
  bf16* y = (z == 0) ? y0 : (z == 1) ? y1 : y2;
  size_t i = ((size_t)blockIdx.x * 256 + threadIdx.x) * 8;
  float4 a = *(const float4*)&x[i];
  float4 b = *(const float4*)&x[i + 4];
  union { bf16 o[8]; bf16x8 v; } u;
  u.o[0] = (bf16)a.x; u.o[1] = (bf16)a.y; u.o[2] = (bf16)a.z; u.o[3] = (bf16)a.w;
  u.o[4] = (bf16)b.x; u.o[5] = (bf16)b.y; u.o[6] = (bf16)b.z; u.o[7] = (bf16)b.w;
  *(bf16x8*)&y[i] = u.v;
}

// ---------------- 256x256 deep-pipelined GEMM (T1+T2+T3+T4+T5) --------------
// C[M,N] = A[M,1024] @ W[N,1024]^T ; BK=64; 512 thr = 8 waves (2M x 4N);
// LDS: 2 dbuf x 256x64 bf16 per matrix = 128 KiB. Per wave: 128x64 C tile.
// Phase shape (template): {reads for THIS phase's MFMA (before barrier);
// [P0 only: burst-stage ALL 8 loads of tile t+1]; BAR; lgkmcnt(0);
// setprio(1); 16 MFMA; setprio(0); BAR}. Reads/phase: 8/4/8/4.
// Pipeline depth: tile t+1's loads issue at t's P0 and are drained by a
// vmcnt(0) at the END of t's P3 (~3.5 phases ≈ 3000 cy later) — the wait
// never targets a fresh load (issue-early equivalent of counted vmcnt).
// LDS swizzle: byte ^= (row&7)<<4 — linear gld_lds dest + inverse-swizzled
// global source + swizzled ds_read (both-sides-or-neither).
#define TSZ (256 * 64)

template <int MODE>  // 0: proj (3x, bf16 scatter [B,H,S,DK]); 1: out (f32 row-major)
__global__ __launch_bounds__(512, 2) void gemm256(
    const bf16* __restrict__ X0, const bf16* __restrict__ X1, const bf16* __restrict__ X2,
    const bf16* __restrict__ W0, const bf16* __restrict__ W1, const bf16* __restrict__ W2,
    const float* __restrict__ b0p, const float* __restrict__ b1p, const float* __restrict__ b2p,
    bf16* __restrict__ Obf0, bf16* __restrict__ Obf1, bf16* __restrict__ Obf2,
    float* __restrict__ Of32) {
  __shared__ __attribute__((aligned(16))) bf16 sA[2 * TSZ];
  __shared__ __attribute__((aligned(16))) bf16 sB[2 * TSZ];

  const int z = blockIdx.z;
  const bf16* X  = (MODE == 1) ? X0 : ((z == 0) ? X0 : (z == 1) ? X1 : X2);
  const bf16* Wt = (MODE == 1) ? W0 : ((z == 0) ? W0 : (z == 1) ? W1 : W2);
  const float* bias = (MODE == 1) ? b0p : ((z == 0) ? b0p : (z == 1) ? b1p : b2p);

  // XCD-aware bijective swizzle: nwg = 4*128 = 512, 512 % 8 == 0.
  const int nx = gridDim.x;
  const int flat = blockIdx.y * nx + blockIdx.x;
  const int cpx = (nx * gridDim.y) >> 3;
  const int swz = (flat & 7) * cpx + (flat >> 3);
  const int M0 = (swz / nx) * 256;
  const int N0 = (swz % nx) * 256;

  const int tid = threadIdx.x, lane = tid & 63, w = tid >> 6;
  const int l15 = lane & 15, l4 = lane >> 4;
  const int wm = w >> 2, wn = w & 3;

  // staging: half-tile = 128 rows x 64 cols; wave w covers rows
  // [w*16, w*16+16) via 2 gld_lds16. LDS dest linear; swizzle applied by
  // permuting the per-lane GLOBAL source column.
  const int lr = lane >> 3;                       // row within 8-row group
  const int scol = ((lane & 7) ^ lr) * 8;         // inverse-swizzled src col
  const size_t aRow = (size_t)(M0 + w * 16 + lr) * NDM + scol;
  const size_t bRow = (size_t)(N0 + w * 16 + lr) * NDM + scol;
  bf16* const dA = sA + (w * 16) * 64;
  bf16* const dB = sB + (w * 16) * 64;

  auto stA = [&](int bufi, int half, int t) {
    const bf16* s = X + aRow + (size_t)half * 128 * NDM + t * 64;
    bf16* d = dA + bufi * TSZ + half * (128 * 64);
    gld_lds16(s, d);
    gld_lds16(s + 8 * NDM, d + 8 * 64);
  };
  auto stB = [&](int bufi, int half, int t) {
    const bf16* s = Wt + bRow + (size_t)half * 128 * NDM + t * 64;
    bf16* d = dB + bufi * TSZ + half * (128 * 64);
    gld_lds16(s, d);
    gld_lds16(s + 8 * NDM, d + 8 * 64);
  };

  f32x4 acc[8][4];
#pragma unroll
  for (int mt = 0; mt < 8; mt++)
#pragma unroll
    for (int nt = 0; nt < 4; nt++) acc[mt][nt] = (f32x4){0.f, 0.f, 0.f, 0.f};

  // swizzled ds_read column offsets (elements); row&7 == l15&7 for all frags
  const int kc0 = (l4 * 8) ^ ((l15 & 7) * 8);
  const int kc1 = (32 + l4 * 8) ^ ((l15 & 7) * 8);
  int arow[8], brow[4];
#pragma unroll
  for (int mt = 0; mt < 8; mt++) arow[mt] = (wm * 128 + mt * 16 + l15) * 64;
#pragma unroll
  for (int nt = 0; nt < 4; nt++) brow[nt] = (wn * 64 + nt * 16 + l15) * 64;

  // prologue: stage tile 0 fully; full drain once (latency exposed once)
  stA(0, 0, 0); stA(0, 1, 0); stB(0, 0, 0); stB(0, 1, 0);
  asm volatile("s_waitcnt vmcnt(0)" ::: "memory");
  barx();

  const int NT = NDM / 64;  // 16
  for (int t = 0; t < NT; ++t) {
    const int cur = t & 1, nxt = cur ^ 1;
    const bf16* cA = sA + cur * TSZ;
    const bf16* cB = sB + cur * TSZ;
    const bool pf = (t + 1 < NT);

    bf16x8 a0[8], b0[4], a1[8], b1[4];

    // ---- P0: reads a0[0..3],b0; burst-stage ALL of tile t+1; MFMA kk0 mt0-3
#pragma unroll
    for (int mt = 0; mt < 4; mt++) a0[mt] = *(const bf16x8*)&cA[arow[mt] + kc0];
#pragma unroll
    for (int nt = 0; nt < 4; nt++) b0[nt] = *(const bf16x8*)&cB[brow[nt] + kc0];
    if (pf) {
      stA(nxt, 0, t + 1); stA(nxt, 1, t + 1);
      stB(nxt, 0, t + 1); stB(nxt, 1, t + 1);
    }
    barx();
    asm volatile("s_waitcnt lgkmcnt(0)" ::: "memory");
    __builtin_amdgcn_sched_barrier(0);
    __builtin_amdgcn_s_setprio(1);
#pragma unroll
    for (int mt = 0; mt < 4; mt++)
#pragma unroll
      for (int nt = 0; nt < 4; nt++) acc[mt][nt] = mfma16(a0[mt], b0[nt], acc[mt][nt]);
    __builtin_amdgcn_s_setprio(0);
    barx();

    // ---- P1: reads a0[4..7]; MFMA kk0 mt4-7
#pragma unroll
    for (int mt = 4; mt < 8; mt++) a0[mt] = *(const bf16x8*)&cA[arow[mt] + kc0];
    barx();
    asm volatile("s_waitcnt lgkmcnt(0)" ::: "memory");
    __builtin_amdgcn_sched_barrier(0);
    __builtin_amdgcn_s_setprio(1);
#pragma unroll
    for (int mt = 4; mt < 8; mt++)
#pragma unroll
      for (int nt = 0; nt < 4; nt++) acc[mt][nt] = mfma16(a0[mt], b0[nt], acc[mt][nt]);
    __builtin_amdgcn_s_setprio(0);
    barx();

    // ---- P2: reads a1[0..3],b1; MFMA kk1 mt0-3
#pragma unroll
    for (int mt = 0; mt < 4; mt++) a1[mt] = *(const bf16x8*)&cA[arow[mt] + kc1];
#pragma unroll
    for (int nt = 0; nt < 4; nt++) b1[nt] = *(const bf16x8*)&cB[brow[nt] + kc1];
    barx();
    asm volatile("s_waitcnt lgkmcnt(0)" ::: "memory");
    __builtin_amdgcn_sched_barrier(0);
    __builtin_amdgcn_s_setprio(1);
#pragma unroll
    for (int mt = 0; mt < 4; mt++)
#pragma unroll
      for (int nt = 0; nt < 4; nt++) acc[mt][nt] = mfma16(a1[mt], b1[nt], acc[mt][nt]);
    __builtin_amdgcn_s_setprio(0);
    barx();

    // ---- P3: reads a1[4..7]; MFMA kk1 mt4-7; drain tile t+1's loads (old)
#pragma unroll
    for (int mt = 4; mt < 8; mt++) a1[mt] = *(const bf16x8*)&cA[arow[mt] + kc1];
    barx();
    asm volatile("s_waitcnt lgkmcnt(0)" ::: "memory");
    __builtin_amdgcn_sched_barrier(0);
    __builtin_amdgcn_s_setprio(1);
#pragma unroll
    for (int mt = 4; mt < 8; mt++)
#pragma unroll
      for (int nt = 0; nt < 4; nt++) acc[mt][nt] = mfma16(a1[mt], b1[nt], acc[mt][nt]);
    __builtin_amdgcn_s_setprio(0);
    asm volatile("s_waitcnt vmcnt(0)" ::: "memory");  // loads are ~3.5 phases old
    barx();
  }

  // ---- epilogue
  if (MODE == 0) {
    bf16* O = (z == 0) ? Obf0 : (z == 1) ? Obf1 : Obf2;
#pragma unroll
    for (int mt = 0; mt < 8; mt++) {
#pragma unroll
      for (int nt = 0; nt < 4; nt++) {
        const int n = N0 + wn * 64 + nt * 16 + l15;
        const float bv_ = bias[n];
        const int h = n >> 7, dk = n & 127;
#pragma unroll
        for (int r = 0; r < 4; r++) {
          const int m = M0 + wm * 128 + mt * 16 + l4 * 4 + r;
          const int b = m >> 7, s = m & 127;
          O[(((size_t)b * NH + h) * NS + s) * NDK + dk] = (bf16)(acc[mt][nt][r] + bv_);
        }
      }
    }
  } else {
#pragma unroll
    for (int mt = 0; mt < 8; mt++) {
#pragma unroll
      for (int nt = 0; nt < 4; nt++) {
        const int n = N0 + wn * 64 + nt * 16 + l15;
        const float bv_ = bias[n];
#pragma unroll
        for (int r = 0; r < 4; r++) {
          const int m = M0 + wm * 128 + mt * 16 + l4 * 4 + r;
          Of32[(size_t)m * NDM + n] = acc[mt][nt][r] + bv_;
        }
      }
    }
  }
}

// ---------------- V tile transpose: [BH][S][DK] -> [BH][DK][S] (bf16) -------
__global__ __launch_bounds__(256) void vt_kernel(const bf16* __restrict__ Vin,
                                                 bf16* __restrict__ Vt) {
  __shared__ __attribute__((aligned(16))) bf16 t[64][72];
  const size_t base = (size_t)blockIdx.z * (NS * NDK);
  const int r0 = blockIdx.y * 64, c0 = blockIdx.x * 64;
  const int tid = threadIdx.x;
  const int tr = tid >> 3, tc8 = tid & 7;
#pragma unroll
  for (int i = 0; i < 2; i++) {
    int r = tr + i * 32;
    *(bf16x8*)&t[r][tc8 * 8] = *(const bf16x8*)&Vin[base + (size_t)(r0 + r) * NDK + c0 + tc8 * 8];
  }
  __syncthreads();
#pragma unroll
  for (int i = 0; i < 2; i++) {
    int c = tr + i * 32;
    bf16x8 o;
#pragma unroll
    for (int k2 = 0; k2 < 8; k2++) o[k2] = t[tc8 * 8 + k2][c];
    *(bf16x8*)&Vt[base + (size_t)(c0 + c) * NS + r0 + tc8 * 8] = o;
  }
}

// ---------------- attention: one block per (b,h) ----------------------------
__global__ __launch_bounds__(256, 1) void attn_kernel(
    const bf16* __restrict__ Qg, const bf16* __restrict__ Kg, const bf16* __restrict__ Vtg,
    const bf16* __restrict__ relq, const bf16* __restrict__ relk, const bf16* __restrict__ relvT,
    const int* __restrict__ qpos, const int* __restrict__ kvpos,
    bf16* __restrict__ ctx) {
  constexpr int LD = 136;
  __shared__ __attribute__((aligned(16))) bf16 R0[128 * LD];
  __shared__ __attribute__((aligned(16))) bf16 R1[128 * LD];
  __shared__ __attribute__((aligned(16))) bf16 R2[128 * LD];
  __shared__ __attribute__((aligned(16))) bf16 R3[128 * LD];

  const int bh = blockIdx.x;
  const int b = bh >> 3, h = bh & 7;
  const int tid = threadIdx.x, lane = tid & 63, w = tid >> 6;
  const int l15 = lane & 15, l4 = lane >> 4;
  const int m0 = w * 32;

  const size_t tb = (size_t)bh * (NS * NDK);
  const bf16* Qp = Qg + tb;
  const bf16* Kp = Kg + tb;
  const bf16* Vp = Vtg + tb;
  const bf16* rq = relq + (size_t)h * NP * NDK;
  const bf16* rk = relk + (size_t)h * NP * NDK;
  const bf16* rv = relvT + (size_t)h * NDK * NP;
  const int* qpp = qpos + (size_t)bh * NS * NS;
  const int* kpp = kvpos + (size_t)bh * NS * NS;

  auto load_tile = [&](bf16* dst, const bf16* src) {
    const int r = tid >> 4, c8 = tid & 15;
#pragma unroll
    for (int i = 0; i < 8; i++) {
      int rr = r + i * 16;
      *(bf16x8*)&dst[rr * LD + c8 * 8] = *(const bf16x8*)&src[rr * 128 + c8 * 8];
    }
  };
  auto gemmNT = [&](const bf16* A, const bf16* Bm, f32x4 (&acc)[2][8]) {
#pragma unroll
    for (int kk = 0; kk < 128; kk += 32) {
      bf16x8 a0 = *(const bf16x8*)&A[(m0 + l15) * LD + kk + l4 * 8];
      bf16x8 a1 = *(const bf16x8*)&A[(m0 + 16 + l15) * LD + kk + l4 * 8];
#pragma unroll
      for (int nt = 0; nt < 8; nt++) {
        bf16x8 bb = *(const bf16x8*)&Bm[(nt * 16 + l15) * LD + kk + l4 * 8];
        acc[0][nt] = mfma16(a0, bb, acc[0][nt]);
        acc[1][nt] = mfma16(a1, bb, acc[1][nt]);
      }
    }
  };

  load_tile(R0, Qp);
  load_tile(R1, Kp);
  load_tile(R2, rq);
  __syncthreads();

  {
    f32x4 acc[2][8];
#pragma unroll
    for (int mt = 0; mt < 2; mt++)
#pragma unroll
      for (int nt = 0; nt < 8; nt++) acc[mt][nt] = (f32x4){0.f, 0.f, 0.f, 0.f};
    gemmNT(R2, R1, acc);
#pragma unroll
    for (int mt = 0; mt < 2; mt++)
#pragma unroll
      for (int nt = 0; nt < 8; nt++)
#pragma unroll
        for (int r = 0; r < 4; r++) {
          int pp = m0 + mt * 16 + l4 * 4 + r;
          int j = nt * 16 + l15;
          R3[pp * LD + j] = (bf16)(acc[mt][nt][r] * kScale);
        }
  }
  f32x4 sc[2][8];
#pragma unroll
  for (int mt = 0; mt < 2; mt++)
#pragma unroll
    for (int nt = 0; nt < 8; nt++) sc[mt][nt] = (f32x4){0.f, 0.f, 0.f, 0.f};
  gemmNT(R0, R1, sc);
  __syncthreads();

  load_tile(R2, rk);
  __syncthreads();

  {
    f32x4 acc[2][8];
#pragma unroll
    for (int mt = 0; mt < 2; mt++)
#pragma unroll
      for (int nt = 0; nt < 8; nt++) acc[mt][nt] = (f32x4){0.f, 0.f, 0.f, 0.f};
    gemmNT(R0, R2, acc);
#pragma unroll
    for (int mt = 0; mt < 2; mt++)
#pragma unroll
      for (int nt = 0; nt < 8; nt++)
#pragma unroll
        for (int r = 0; r < 4; r++) {
          int i = m0 + mt * 16 + l4 * 4 + r;
          int pp = nt * 16 + l15;
          R1[i * LD + pp] = (bf16)(acc[mt][nt][r] * kScale);
        }
  }

  unsigned long long keep = 0ull;
#pragma unroll
  for (int mt = 0; mt < 2; mt++)
#pragma unroll
    for (int nt = 0; nt < 8; nt++)
#pragma unroll
      for (int r = 0; r < 4; r++) {
        int i = m0 + mt * 16 + l4 * 4 + r;
        int j = nt * 16 + l15;
        int qv = qpp[i * NS + j];
        int kv = kpp[i * NS + j];
        float v = sc[mt][nt][r] * kScale + (float)R3[qv * LD + j] + (float)R1[i * LD + kv];
        sc[mt][nt][r] = v;
        if (qv == 0 || i == 0) keep |= 1ull << (mt * 32 + nt * 4 + r);
      }
  float rmx[2][4];
#pragma unroll
  for (int mt = 0; mt < 2; mt++)
#pragma unroll
    for (int r = 0; r < 4; r++) {
      float m = -3.0e38f;
#pragma unroll
      for (int nt = 0; nt < 8; nt++) m = fmaxf(m, sc[mt][nt][r]);
      rmx[mt][r] = red16_max(m);
    }
#pragma unroll
  for (int mt = 0; mt < 2; mt++)
#pragma unroll
    for (int nt = 0; nt < 8; nt++)
#pragma unroll
      for (int r = 0; r < 4; r++) {
        float v = sc[mt][nt][r] - rmx[mt][r];
        if (!((keep >> (mt * 32 + nt * 4 + r)) & 1ull)) v = kNeg;
        sc[mt][nt][r] = v;
      }
  float m2[2][4], inv[2][4];
#pragma unroll
  for (int mt = 0; mt < 2; mt++)
#pragma unroll
    for (int r = 0; r < 4; r++) {
      float m = -3.0e38f;
#pragma unroll
      for (int nt = 0; nt < 8; nt++) m = fmaxf(m, sc[mt][nt][r]);
      m2[mt][r] = red16_max(m);
    }
#pragma unroll
  for (int mt = 0; mt < 2; mt++)
#pragma unroll
    for (int nt = 0; nt < 8; nt++)
#pragma unroll
      for (int r = 0; r < 4; r++) sc[mt][nt][r] = __expf(sc[mt][nt][r] - m2[mt][r]);
#pragma unroll
  for (int mt = 0; mt < 2; mt++)
#pragma unroll
    for (int r = 0; r < 4; r++) {
      float s = 0.f;
#pragma unroll
      for (int nt = 0; nt < 8; nt++) s += sc[mt][nt][r];
      inv[mt][r] = 1.0f / red16_sum(s);
    }
#pragma unroll
  for (int mt = 0; mt < 2; mt++)
#pragma unroll
    for (int nt = 0; nt < 8; nt++)
#pragma unroll
      for (int r = 0; r < 4; r++) sc[mt][nt][r] *= inv[mt][r];
  __syncthreads();

#pragma unroll
  for (int mt = 0; mt < 2; mt++)
#pragma unroll
    for (int nt = 0; nt < 8; nt++)
#pragma unroll
      for (int r = 0; r < 4; r++) {
        int i = m0 + mt * 16 + l4 * 4 + r;
        int j = nt * 16 + l15;
        R3[i * LD + j] = (bf16)sc[mt][nt][r];
      }
  load_tile(R0, Vp);
  load_tile(R1, rv);
  __syncthreads();

  {
    f32x4 acc2[2][8];
#pragma unroll
    for (int mt = 0; mt < 2; mt++)
#pragma unroll
      for (int nt = 0; nt < 8; nt++) acc2[mt][nt] = (f32x4){0.f, 0.f, 0.f, 0.f};
    gemmNT(R3, R1, acc2);
#pragma unroll
    for (int mt = 0; mt < 2; mt++)
#pragma unroll
      for (int nt = 0; nt < 8; nt++)
#pragma unroll
        for (int r = 0; r < 4; r++) {
          int i = m0 + mt * 16 + l4 * 4 + r;
          int d = nt * 16 + l15;
          R2[i * LD + d] = (bf16)acc2[mt][nt][r];
        }
  }
  {
    f32x4 acc1[2][8];
#pragma unroll
    for (int mt = 0; mt < 2; mt++)
#pragma unroll
      for (int nt = 0; nt < 8; nt++) acc1[mt][nt] = (f32x4){0.f, 0.f, 0.f, 0.f};
    gemmNT(R3, R0, acc1);
#pragma unroll
    for (int mt = 0; mt < 2; mt++)
#pragma unroll
      for (int nt = 0; nt < 8; nt++)
#pragma unroll
        for (int r = 0; r < 4; r++) {
          int i = m0 + mt * 16 + l4 * 4 + r;
          int d = nt * 16 + l15;
          int kv = kpp[i * NS + d];
          float v = acc1[mt][nt][r] + (float)R2[i * LD + kv];
          ctx[(((size_t)b * NS + i) * NH + h) * NDK + d] = (bf16)v;
        }
  }
}

extern "C" void kernel_launch(void* const* d_in, const int* in_sizes, int n_in,
                              void* d_out, int out_size, void* d_ws, size_t ws_size,
                              hipStream_t stream) {
  const float* query = (const float*)d_in[0];
  const float* key   = (const float*)d_in[1];
  const float* value = (const float*)d_in[2];
  const int* qpos    = (const int*)d_in[3];
  const int* kvpos   = (const int*)d_in[4];
  const float* rel_q = (const float*)d_in[5];
  const float* rel_k = (const float*)d_in[6];
  const float* rel_v = (const float*)d_in[7];
  const float* Wq = (const float*)d_in[8];
  const float* bq = (const float*)d_in[9];
  const float* Wk = (const float*)d_in[10];
  const float* bk = (const float*)d_in[11];
  const float* Wv = (const float*)d_in[12];
  const float* bv = (const float*)d_in[13];
  const float* Wo = (const float*)d_in[14];
  const float* bo = (const float*)d_in[15];
  float* out = (float*)d_out;

  char* p = (char*)d_ws;
  size_t off = 0;
  auto take = [&](size_t n) {
    char* r = p + off;
    off += (n + 255) & ~(size_t)255;
    return r;
  };
  bf16* Wtq = (bf16*)take((size_t)NDM * NDM * 2);
  bf16* Wtk = (bf16*)take((size_t)NDM * NDM * 2);
  bf16* Wtv = (bf16*)take((size_t)NDM * NDM * 2);
  bf16* Wto = (bf16*)take((size_t)NDM * NDM * 2);
  bf16* rqb = (bf16*)take((size_t)NH * NP * NDK * 2);
  bf16* rkb = (bf16*)take((size_t)NH * NP * NDK * 2);
  bf16* rvt = (bf16*)take((size_t)NH * NDK * NP * 2);
  const size_t big = (size_t)NB * NH * NS * NDK * 2;  // 64 MiB
  bf16* qws  = (bf16*)take(big);
  bf16* kws  = (bf16*)take(big);
  bf16* vws  = (bf16*)take(big);
  bf16* vtws = (bf16*)take(big);
  bf16* ctxw = (bf16*)take(big);
  bf16* xtra = (bf16*)take(big);
  // cast buffers alias later-life buffers (dead before vt/attn write them):
  bf16* xq = vtws;  // vtws written only in vt_kernel (after proj)
  bf16* xk = ctxw;  // ctxw written only in attn (after proj)
  bf16* xv = xtra;

  hipLaunchKernelGGL(prep_kernel, dim3(16, 16, 6), dim3(256), 0, stream,
                     Wq, Wk, Wv, Wo, rel_q, rel_k, rel_v,
                     Wtq, Wtk, Wtv, Wto, rqb, rkb, rvt);
  hipLaunchKernelGGL(cast_kernel, dim3((NB * NS * NDM) / (256 * 8), 1, 3), dim3(256), 0, stream,
                     query, key, value, xq, xk, xv);
  hipLaunchKernelGGL((gemm256<0>), dim3(4, 128, 3), dim3(512), 0, stream,
                     xq, xk, xv, Wtq, Wtk, Wtv, bq, bk, bv, qws, kws, vws, (float*)nullptr);
  hipLaunchKernelGGL(vt_kernel, dim3(2, 2, NB * NH), dim3(256), 0, stream, vws, vtws);
  hipLaunchKernelGGL(attn_kernel, dim3(NB * NH), dim3(256), 0, stream,
                     qws, kws, vtws, rqb, rkb, rvt, qpos, kvpos, ctxw);
  hipLaunchKernelGGL((gemm256<1>), dim3(4, 128), dim3(512), 0, stream,
                     ctxw, (const bf16*)nullptr, (const bf16*)nullptr,
                     Wto, (const bf16*)nullptr, (const bf16*)nullptr,
                     bo, (const float*)nullptr, (const float*)nullptr,
                     (bf16*)nullptr, (bf16*)nullptr, (bf16*)nullptr, out);
}